// Round 3
// 6713.229 us; speedup vs baseline: 1.5346x; 1.5346x over previous
//
#include <hip/hip_runtime.h>
#include <math.h>
#include <stdint.h>

// Problem constants
#define Bb 32
#define Ss 512
#define Dd 1024
#define Hh 16
#define HDd 64
#define Ll 6
#define DFFd 4096
#define Pp 64
#define BS (Bb * Ss)   // 16384 token rows

typedef _Float16 f16;
typedef _Float16 f16x8 __attribute__((ext_vector_type(8)));
typedef float f32x4 __attribute__((ext_vector_type(4)));

typedef __attribute__((address_space(3))) uint8_t  lds_b;
typedef __attribute__((address_space(1))) const uint8_t gbl_b;

// ---------------------------------------------------------------------------
// NT GEMM: C[M,N] = act( scale * A[M,K] @ Bt[N,K]^T + bias + pvec ) (* mul)
// (unchanged from verified baseline; used for QKV/outproj/FFN)
// ---------------------------------------------------------------------------
template <bool BIAS, bool PVEC, bool MULV, bool RELU>
__global__ __launch_bounds__(256) void gemm_nt(
    const f16* __restrict__ A, const f16* __restrict__ Bt, f16* __restrict__ C,
    int M, int N, int K, int lda, int ldb, int ldc,
    long sA1, long sA2, long sB1, long sB2, long sC1, long sC2, int nz2,
    const float* __restrict__ bias, const float* __restrict__ pvec, int pvs,
    const float* __restrict__ mul, long sM1, long sM2, float scale)
{
    __shared__ f16 As[128 * 32];   // row-major [128][32], swizzled 16B chunks
    __shared__ f16 Bs[128 * 32];

    int z = blockIdx.z;
    int z1 = z / nz2, z2 = z % nz2;
    A  += z1 * sA1 + z2 * sA2;
    Bt += z1 * sB1 + z2 * sB2;
    long coff = z1 * sC1 + z2 * sC2;
    if (MULV) mul += z1 * sM1 + z2 * sM2;

    int m0 = blockIdx.x * 128, n0 = blockIdx.y * 128;
    int t = threadIdx.x;
    int lane = t & 63, w = t >> 6;
    int wm = (w >> 1) * 64, wn = (w & 1) * 64;
    int fr = lane & 15;            // A row / B col within 16-tile
    int fs = lane >> 4;            // k-segment (8 halves each)
    int fsw = fs ^ ((fr >> 1) & 3);   // swizzled chunk for fragment reads

    int srow = t >> 2;
    int gch = (t & 3) ^ ((srow >> 1) & 3);
    int gmS0 = m0 + srow;       if (gmS0 >= M) gmS0 = M - 1;
    int gmS1 = m0 + 64 + srow;  if (gmS1 >= M) gmS1 = M - 1;
    int gnS0 = n0 + srow;       if (gnS0 >= N) gnS0 = N - 1;
    int gnS1 = n0 + 64 + srow;  if (gnS1 >= N) gnS1 = N - 1;
    const f16* aRow0 = A + (long)gmS0 * lda + gch * 8;
    const f16* aRow1 = A + (long)gmS1 * lda + gch * 8;
    const f16* bRow0 = Bt + (long)gnS0 * ldb + gch * 8;
    const f16* bRow1 = Bt + (long)gnS1 * ldb + gch * 8;
    lds_b* aDst = (lds_b*)As + w * 1024;
    lds_b* bDst = (lds_b*)Bs + w * 1024;

    f32x4 acc[4][4] = {};

    for (int k0 = 0; k0 < K; k0 += 32) {
        __syncthreads();
        __builtin_amdgcn_global_load_lds((gbl_b*)(aRow0 + k0), aDst, 16, 0, 0);
        __builtin_amdgcn_global_load_lds((gbl_b*)(aRow1 + k0), aDst + 4096, 16, 0, 0);
        __builtin_amdgcn_global_load_lds((gbl_b*)(bRow0 + k0), bDst, 16, 0, 0);
        __builtin_amdgcn_global_load_lds((gbl_b*)(bRow1 + k0), bDst + 4096, 16, 0, 0);
        __syncthreads();
        f16x8 af[4], bf[4];
        #pragma unroll
        for (int i = 0; i < 4; ++i) af[i] = *(const f16x8*)&As[(wm + i * 16 + fr) * 32 + fsw * 8];
        #pragma unroll
        for (int j = 0; j < 4; ++j) bf[j] = *(const f16x8*)&Bs[(wn + j * 16 + fr) * 32 + fsw * 8];
        #pragma unroll
        for (int i = 0; i < 4; ++i)
            #pragma unroll
            for (int j = 0; j < 4; ++j)
                acc[i][j] = __builtin_amdgcn_mfma_f32_16x16x32_f16(af[i], bf[j], acc[i][j], 0, 0, 0);
    }

    int cr = (lane >> 4) * 4;
    int cc = lane & 15;
    #pragma unroll
    for (int i = 0; i < 4; ++i) {
        #pragma unroll
        for (int j = 0; j < 4; ++j) {
            int gn = n0 + wn + j * 16 + cc;
            if (gn >= N) continue;
            float bvv = BIAS ? bias[gn] : 0.f;
            float mvv = MULV ? mul[gn] : 1.f;
            #pragma unroll
            for (int r = 0; r < 4; ++r) {
                int gm = m0 + wm + i * 16 + cr + r;
                if (gm >= M) continue;
                float v = acc[i][j][r] * scale + bvv;
                if (PVEC) v += pvec[(long)(gm >> pvs) * N + gn];
                if (MULV) v *= mvv;
                if (RELU) v = fmaxf(v, 0.f);
                C[coff + (long)gm * ldc + gn] = (f16)v;
            }
        }
    }
}

// ---------------------------------------------------------------------------
// Fused flash attention for one (b,h): O[b,s,h*64+d] = gate[b,h*64+d] *
//   ( softmax(Q K^T / 8 + maskbias) V )[s,d]
// Grid (S/128, B*H), 256 threads = 4 waves; wave w owns 32 q-rows.
// K tile [64 s][64 hd] and V^T tile [64 hd][64 s] staged via global_load_lds
// (16B chunks, chunk ^= row&7 XOR swizzle). Online softmax in registers:
// C-layout lane holds S[q=i*16+cr+r, k=j*16+cc]; row reduce = 4-step shfl_xor
// inside the 16-lane group. P goes through a per-wave [32][72]-padded LDS
// tile to reach MFMA A-fragment layout.
// ---------------------------------------------------------------------------
__global__ __launch_bounds__(256) void fused_attn(
    const f16* __restrict__ Q, const f16* __restrict__ K,
    const f16* __restrict__ Vt, const int* __restrict__ mask,
    const float* __restrict__ gate, f16* __restrict__ O)
{
    __shared__ f16 Ks[64 * 64];      // [s][hd], swizzled 16B chunks
    __shared__ f16 Vs[64 * 64];      // [hd][s], swizzled 16B chunks
    __shared__ float maskb[Ss];
    __shared__ f16 Ps[4][32 * 72];   // per-wave P tile, rows padded to 72 halves

    int t = threadIdx.x;
    int lane = t & 63, w = t >> 6;
    int bh = blockIdx.y, b = bh >> 4, h = bh & 15;
    int q0 = blockIdx.x * 128 + w * 32;

    int fr = lane & 15, fs = lane >> 4;
    int cr = fs * 4, cc = fr;

    for (int i = t; i < Ss; i += 256)
        maskb[i] = mask[b * Ss + i] ? 0.f : -1e9f;

    // Q fragments straight from global (one-time)
    f16x8 qf[2][2];
    {
        const f16* qb = Q + (long)(b * Ss + q0 + fr) * Dd + h * HDd + fs * 8;
        #pragma unroll
        for (int i = 0; i < 2; ++i)
            #pragma unroll
            for (int ks = 0; ks < 2; ++ks)
                qf[i][ks] = *(const f16x8*)(qb + (long)i * 16 * Dd + ks * 32);
    }

    // staging: thread t covers tile (row=t>>3, chunk=t&7); global chunk XORed.
    // (row+32)&7 == row&7, so one gch serves both 32-row halves.
    int srow = t >> 3;
    int gch = (t & 7) ^ (srow & 7);
    const f16* kB = K + (long)(b * Ss + srow) * Dd + h * HDd + gch * 8;
    const f16* vB = Vt + ((long)bh * HDd + srow) * Ss + gch * 8;
    lds_b* kDst = (lds_b*)Ks + w * 1024;
    lds_b* vDst = (lds_b*)Vs + w * 1024;

    f32x4 oacc[2][4] = {};
    float m_[8], l_[8];
    #pragma unroll
    for (int x = 0; x < 8; ++x) { m_[x] = -1e30f; l_[x] = 0.f; }

    for (int tt = 0; tt < Ss / 64; ++tt) {
        __syncthreads();   // previous tile's LDS reads done before overwrite
        __builtin_amdgcn_global_load_lds((gbl_b*)(kB + (long)tt * 64 * Dd), kDst, 16, 0, 0);
        __builtin_amdgcn_global_load_lds((gbl_b*)(kB + (long)tt * 64 * Dd + 32 * Dd), kDst + 4096, 16, 0, 0);
        __builtin_amdgcn_global_load_lds((gbl_b*)(vB + tt * 64), vDst, 16, 0, 0);
        __builtin_amdgcn_global_load_lds((gbl_b*)(vB + tt * 64 + 32 * Ss), vDst + 4096, 16, 0, 0);
        __syncthreads();   // staging drained (vmcnt0 before barrier)

        // S = Q K^T  (16 mfma)
        f16x8 kf[4][2];
        #pragma unroll
        for (int j = 0; j < 4; ++j) {
            int row = j * 16 + fr;
            #pragma unroll
            for (int ks = 0; ks < 2; ++ks)
                kf[j][ks] = *(const f16x8*)&Ks[row * 64 + (((ks * 4 + fs) ^ (row & 7)) * 8)];
        }
        f32x4 sacc[2][4] = {};
        #pragma unroll
        for (int i = 0; i < 2; ++i)
            #pragma unroll
            for (int j = 0; j < 4; ++j)
                #pragma unroll
                for (int ks = 0; ks < 2; ++ks)
                    sacc[i][j] = __builtin_amdgcn_mfma_f32_16x16x32_f16(qf[i][ks], kf[j][ks], sacc[i][j], 0, 0, 0);

        float mb[4];
        #pragma unroll
        for (int j = 0; j < 4; ++j) mb[j] = maskb[tt * 64 + j * 16 + cc];

        // online softmax + P -> LDS (fp16)
        #pragma unroll
        for (int i = 0; i < 2; ++i) {
            #pragma unroll
            for (int r = 0; r < 4; ++r) {
                float s0 = sacc[i][0][r] * 0.125f + mb[0];
                float s1 = sacc[i][1][r] * 0.125f + mb[1];
                float s2 = sacc[i][2][r] * 0.125f + mb[2];
                float s3 = sacc[i][3][r] * 0.125f + mb[3];
                float tm = fmaxf(fmaxf(s0, s1), fmaxf(s2, s3));
                #pragma unroll
                for (int o = 1; o < 16; o <<= 1) tm = fmaxf(tm, __shfl_xor(tm, o, 64));
                int ix = i * 4 + r;
                float mn = fmaxf(m_[ix], tm);
                float resc = __expf(m_[ix] - mn);   // first tile: exp(-1e30-mn)=0
                m_[ix] = mn;
                float p0 = __expf(s0 - mn), p1 = __expf(s1 - mn);
                float p2 = __expf(s2 - mn), p3 = __expf(s3 - mn);
                float ts = (p0 + p1) + (p2 + p3);
                #pragma unroll
                for (int o = 1; o < 16; o <<= 1) ts += __shfl_xor(ts, o, 64);
                l_[ix] = l_[ix] * resc + ts;
                #pragma unroll
                for (int j = 0; j < 4; ++j) oacc[i][j][r] *= resc;
                int qrow = (i * 16 + cr + r) * 72;
                Ps[w][qrow + cc]      = (f16)p0;
                Ps[w][qrow + 16 + cc] = (f16)p1;
                Ps[w][qrow + 32 + cc] = (f16)p2;
                Ps[w][qrow + 48 + cc] = (f16)p3;
            }
        }

        // O += P V  (16 mfma); Ps is wave-private, compiler inserts lgkmcnt
        f16x8 pf[2][2], vf[4][2];
        #pragma unroll
        for (int i = 0; i < 2; ++i)
            #pragma unroll
            for (int ks = 0; ks < 2; ++ks)
                pf[i][ks] = *(const f16x8*)&Ps[w][(i * 16 + fr) * 72 + ks * 32 + fs * 8];
        #pragma unroll
        for (int j = 0; j < 4; ++j) {
            int row = j * 16 + fr;
            #pragma unroll
            for (int ks = 0; ks < 2; ++ks)
                vf[j][ks] = *(const f16x8*)&Vs[row * 64 + (((ks * 4 + fs) ^ (row & 7)) * 8)];
        }
        #pragma unroll
        for (int i = 0; i < 2; ++i)
            #pragma unroll
            for (int j = 0; j < 4; ++j)
                #pragma unroll
                for (int ks = 0; ks < 2; ++ks)
                    oacc[i][j] = __builtin_amdgcn_mfma_f32_16x16x32_f16(pf[i][ks], vf[j][ks], oacc[i][j], 0, 0, 0);
    }

    // epilogue: normalize, gate, store
    float gv[4];
    #pragma unroll
    for (int j = 0; j < 4; ++j) gv[j] = gate[(long)b * Dd + h * HDd + j * 16 + cc];
    #pragma unroll
    for (int i = 0; i < 2; ++i) {
        #pragma unroll
        for (int r = 0; r < 4; ++r) {
            float inv = 1.f / l_[i * 4 + r];
            long orow = (long)(b * Ss + q0 + i * 16 + cr + r) * Dd + h * HDd;
            #pragma unroll
            for (int j = 0; j < 4; ++j)
                O[orow + j * 16 + cc] = (f16)(oacc[i][j][r] * inv * gv[j]);
        }
    }
}

// fp32 [K,N] -> fp16 [N,K] transpose (weights), K,N multiples of 32
__global__ __launch_bounds__(256) void transpose_w(
    const float* __restrict__ W, f16* __restrict__ Wt, int K, int N)
{
    __shared__ float tile[32][33];
    int k0 = blockIdx.x * 32, n0 = blockIdx.y * 32;
    int tx = threadIdx.x & 31, ty = threadIdx.x >> 5;
    #pragma unroll
    for (int i = ty; i < 32; i += 8)
        tile[i][tx] = W[(long)(k0 + i) * N + n0 + tx];
    __syncthreads();
    #pragma unroll
    for (int i = ty; i < 32; i += 8)
        Wt[(long)(n0 + i) * K + k0 + tx] = (f16)tile[tx][i];
}

// V [B,S,D] fp16 -> vt [B,H,HD,S] fp16
__global__ __launch_bounds__(256) void transpose_v(
    const f16* __restrict__ V, f16* __restrict__ vt)
{
    int z = blockIdx.z, b = z >> 4, h = z & 15;
    __shared__ f16 tile[32][33];
    int s0 = blockIdx.x * 32, d0 = blockIdx.y * 32;
    int tx = threadIdx.x & 31, ty = threadIdx.x >> 5;
    #pragma unroll
    for (int i = ty; i < 32; i += 8)
        tile[i][tx] = V[((long)b * Ss + s0 + i) * Dd + h * HDd + d0 + tx];
    __syncthreads();
    #pragma unroll
    for (int i = ty; i < 32; i += 8)
        vt[(((long)b * Hh + h) * HDd + d0 + i) * Ss + s0 + tx] = tile[tx][i];
}

// embedding * sqrt(D) + sinusoidal posenc -> xh fp16
__global__ __launch_bounds__(256) void embed_pe(
    const int* __restrict__ tok, const float* __restrict__ emb,
    f16* __restrict__ xh)
{
    int bs = blockIdx.x;
    int s = bs & (Ss - 1);
    int tk = tok[bs];
    const float c = -logf(10000.f) / (float)Dd;
    for (int d = threadIdx.x; d < Dd; d += 256) {
        float div = expf((float)(d & ~1) * c);
        float ang = (float)s * div;
        float pe = (d & 1) ? cosf(ang) : sinf(ang);
        float v = emb[(long)tk * Dd + d] * 32.0f + pe;  // sqrt(1024)=32
        xh[(long)bs * Dd + d] = (f16)v;
    }
}

// x = LN(x + y) * g + b ; fp16 in/out (in-place safe: reads before writes)
__global__ __launch_bounds__(256) void add_ln(
    const f16* __restrict__ x, const f16* __restrict__ y,
    const float* __restrict__ g, const float* __restrict__ b,
    f16* __restrict__ xo)
{
    __shared__ float red[8];
    long row = blockIdx.x;
    const f16* xr = x + row * Dd;
    const f16* yr = y + row * Dd;
    float vals[4];
    float s = 0.f, s2 = 0.f;
    #pragma unroll
    for (int i = 0; i < 4; ++i) {
        int cix = threadIdx.x + i * 256;
        float v = (float)xr[cix] + (float)yr[cix];
        vals[i] = v;
        s += v; s2 += v * v;
    }
    #pragma unroll
    for (int o = 32; o > 0; o >>= 1) {
        s  += __shfl_down(s, o, 64);
        s2 += __shfl_down(s2, o, 64);
    }
    if ((threadIdx.x & 63) == 0) {
        red[threadIdx.x >> 6] = s;
        red[4 + (threadIdx.x >> 6)] = s2;
    }
    __syncthreads();
    s  = red[0] + red[1] + red[2] + red[3];
    s2 = red[4] + red[5] + red[6] + red[7];
    float mu = s * (1.f / Dd);
    float var = s2 * (1.f / Dd) - mu * mu;
    float inv = rsqrtf(var + 1e-5f);
    #pragma unroll
    for (int i = 0; i < 4; ++i) {
        int cix = threadIdx.x + i * 256;
        float o = (vals[i] - mu) * inv * g[cix] + b[cix];
        xo[row * Dd + cix] = (f16)o;
    }
}

// out[b,n] = act(pv[b,:] @ W[:,n] + bias[n]) ; K=P=64, N=D. ACT: 0 none, 1 sigmoid
template <int ACT>
__global__ __launch_bounds__(256) void pv_proj(
    const float* __restrict__ pv, const float* __restrict__ W,
    const float* __restrict__ bias, float* __restrict__ out)
{
    int n = blockIdx.x * 256 + threadIdx.x;
    int b = blockIdx.y;
    float acc = bias[n];
    #pragma unroll 8
    for (int k = 0; k < Pp; ++k)
        acc += pv[b * Pp + k] * W[(long)k * Dd + n];
    if (ACT == 1) acc = 1.f / (1.f + expf(-acc));
    out[(long)b * Dd + n] = acc;
}

// masked mean pool over S (f16 in, fp32 out)
__global__ __launch_bounds__(256) void pool_mean(
    const f16* __restrict__ x, const int* __restrict__ mask, float* __restrict__ out)
{
    int d = blockIdx.x * 256 + threadIdx.x;
    int b = blockIdx.y;
    float s = 0.f, cnt = 0.f;
    for (int ss = 0; ss < Ss; ++ss) {
        if (mask[b * Ss + ss]) { s += (float)x[((long)b * Ss + ss) * Dd + d]; cnt += 1.f; }
    }
    out[(long)b * Dd + d] = s / fmaxf(cnt, 1e-9f);
}

// small fp32 GEMM for the head: C[m,n] = act(A[m,:]@W[:,n] + bias[n] (+ add[m,n]))
template <int ACT>
__global__ __launch_bounds__(256) void small_gemm(
    const float* __restrict__ A, const float* __restrict__ W,
    const float* __restrict__ bias, const float* __restrict__ add,
    float* __restrict__ C, int N, int K)
{
    __shared__ float a[1024];
    int m = blockIdx.y;
    int n = blockIdx.x * 256 + threadIdx.x;
    for (int k = threadIdx.x; k < K; k += 256) a[k] = A[(long)m * K + k];
    __syncthreads();
    float acc = bias[n];
    for (int k = 0; k < K; ++k) acc += a[k] * W[(long)k * N + n];
    if (add) acc += add[(long)m * N + n];
    if (ACT == 1) acc = fmaxf(acc, 0.f);
    if (ACT == 2) acc = tanhf(acc);
    C[(long)m * N + n] = acc;
}

extern "C" void kernel_launch(void* const* d_in, const int* in_sizes, int n_in,
                              void* d_out, int out_size, void* d_ws, size_t ws_size,
                              hipStream_t stream) {
    const int*   tok  = (const int*)d_in[0];
    const int*   mask = (const int*)d_in[1];
    const float* pv   = (const float*)d_in[2];
    const float* emb  = (const float*)d_in[3];
    const float* Wq  = (const float*)d_in[4];  const float* bq  = (const float*)d_in[5];
    const float* Wk  = (const float*)d_in[6];  const float* bk  = (const float*)d_in[7];
    const float* Wv  = (const float*)d_in[8];  const float* bvp = (const float*)d_in[9];
    const float* Wo  = (const float*)d_in[10]; const float* bo  = (const float*)d_in[11];
    const float* Wpq = (const float*)d_in[12]; const float* bpq = (const float*)d_in[13];
    const float* Wpk = (const float*)d_in[14]; const float* bpk = (const float*)d_in[15];
    const float* Wpg = (const float*)d_in[16]; const float* bpg = (const float*)d_in[17];
    const float* Wf1 = (const float*)d_in[18]; const float* bf1 = (const float*)d_in[19];
    const float* Wf2 = (const float*)d_in[20]; const float* bf2 = (const float*)d_in[21];
    const float* g1  = (const float*)d_in[22]; const float* b1  = (const float*)d_in[23];
    const float* g2  = (const float*)d_in[24]; const float* b2  = (const float*)d_in[25];
    const float* Wp1 = (const float*)d_in[26]; const float* bp1 = (const float*)d_in[27];
    const float* Wp2 = (const float*)d_in[28]; const float* bp2 = (const float*)d_in[29];
    const float* Wo1 = (const float*)d_in[30]; const float* bo1 = (const float*)d_in[31];
    const float* Wo2 = (const float*)d_in[32]; const float* bo2 = (const float*)d_in[33];
    float* outp = (float*)d_out;

    // ---- workspace carve: total ~249 MiB ----
    char* wp = (char*)d_ws;
    auto alloc = [&](size_t bytes) { char* r = wp; wp += (bytes + 255) & ~(size_t)255; return r; };
    const long DDl = (long)Dd * Dd;
    // per-layer transposed weights (fp16 [N,K])
    f16* wqT  = (f16*)alloc(DDl * 2);                      // 2 MiB
    f16* wkT  = (f16*)alloc(DDl * 2);
    f16* wvT  = (f16*)alloc(DDl * 2);
    f16* woT  = (f16*)alloc(DDl * 2);
    f16* wf1T = (f16*)alloc((size_t)DFFd * Dd * 2);        // 8 MiB
    f16* wf2T = (f16*)alloc((size_t)Dd * DFFd * 2);        // 8 MiB
    // activations (fp16). qh/kh/vt/attg are contiguous 128 MiB, reused as ff1.
    f16* xh   = (f16*)alloc((size_t)BS * Dd * 2);          // 32 MiB residual stream
    f16* qh   = (f16*)alloc((size_t)BS * Dd * 2);          // 32 MiB
    f16* kh   = (f16*)alloc((size_t)BS * Dd * 2);          // 32 MiB
    f16* vt   = (f16*)alloc((size_t)BS * Dd * 2);          // 32 MiB [B,H,HD,S]
    f16* attg = (f16*)alloc((size_t)BS * Dd * 2);          // 32 MiB gated attn out
    // region A (32 MiB): vh [BS,D] (scratch for V projection)
    f16* regA = (f16*)alloc((size_t)BS * Dd * 2);
    f16* vh = regA;
    // tmp (32 MiB fp16): outproj / FFN2 results, consumed by add_ln
    f16* tmp  = (f16*)alloc((size_t)BS * Dd * 2);
    // small fp32 buffers
    float* pq     = (float*)alloc((size_t)Bb * Dd * 4);
    float* pk     = (float*)alloc((size_t)Bb * Dd * 4);
    float* gate   = (float*)alloc((size_t)Bb * Dd * 4);
    float* pooled = (float*)alloc((size_t)Bb * Dd * 4);
    float* h1v    = (float*)alloc((size_t)Bb * Dd * 4);
    float* comb   = (float*)alloc((size_t)Bb * Dd * 4);
    float* tvv    = (float*)alloc((size_t)Bb * Dd * 4);

    f16* ffbig = qh;   // 16384 x 4096 fp16 spans qh..attg (all dead during FFN)

    dim3 blk(256);

    // ---- embedding + posenc ----
    embed_pe<<<dim3(BS), blk, 0, stream>>>(tok, emb, xh);

    for (int l = 0; l < Ll; ++l) {
        // per-layer weight transposes (fp32 [K,N] -> fp16 [N,K])
        transpose_w<<<dim3(32, 32), blk, 0, stream>>>(Wq + l * DDl, wqT, Dd, Dd);
        transpose_w<<<dim3(32, 32), blk, 0, stream>>>(Wk + l * DDl, wkT, Dd, Dd);
        transpose_w<<<dim3(32, 32), blk, 0, stream>>>(Wv + l * DDl, wvT, Dd, Dd);
        transpose_w<<<dim3(32, 32), blk, 0, stream>>>(Wo + l * DDl, woT, Dd, Dd);
        transpose_w<<<dim3(32, 128), blk, 0, stream>>>(Wf1 + (long)l * Dd * DFFd, wf1T, Dd, DFFd);
        transpose_w<<<dim3(128, 32), blk, 0, stream>>>(Wf2 + (long)l * DFFd * Dd, wf2T, DFFd, Dd);

        // per-batch property projections
        pv_proj<0><<<dim3(4, Bb), blk, 0, stream>>>(pv, Wpq + (long)l * Pp * Dd, bpq + l * Dd, pq);
        pv_proj<0><<<dim3(4, Bb), blk, 0, stream>>>(pv, Wpk + (long)l * Pp * Dd, bpk + l * Dd, pk);
        pv_proj<1><<<dim3(4, Bb), blk, 0, stream>>>(pv, Wpg + (long)l * Pp * Dd, bpg + l * Dd, gate);

        // Q/K/V projections -> fp16 [B,S,D]
        gemm_nt<true, true, false, false><<<dim3(128, 8, 1), blk, 0, stream>>>(
            xh, wqT, qh, BS, Dd, Dd, Dd, Dd, Dd,
            0, 0, 0, 0, 0, 0, 1, bq + l * Dd, pq, 9, nullptr, 0, 0, 1.0f);
        gemm_nt<true, true, false, false><<<dim3(128, 8, 1), blk, 0, stream>>>(
            xh, wkT, kh, BS, Dd, Dd, Dd, Dd, Dd,
            0, 0, 0, 0, 0, 0, 1, bk + l * Dd, pk, 9, nullptr, 0, 0, 1.0f);
        gemm_nt<true, false, false, false><<<dim3(128, 8, 1), blk, 0, stream>>>(
            xh, wvT, vh, BS, Dd, Dd, Dd, Dd, Dd,
            0, 0, 0, 0, 0, 0, 1, bvp + l * Dd, nullptr, 0, nullptr, 0, 0, 1.0f);

        transpose_v<<<dim3(16, 2, Bb * Hh), blk, 0, stream>>>(vh, vt);

        // fused flash attention (scores never touch memory; gate fused)
        fused_attn<<<dim3(4, Bb * Hh), blk, 0, stream>>>(qh, kh, vt, mask, gate, attg);

        // output projection -> fp16 tmp, then residual+LN (in-place on xh)
        gemm_nt<true, false, false, false><<<dim3(128, 8, 1), blk, 0, stream>>>(
            attg, woT, tmp, BS, Dd, Dd, Dd, Dd, Dd,
            0, 0, 0, 0, 0, 0, 1, bo + l * Dd, nullptr, 0, nullptr, 0, 0, 1.0f);
        add_ln<<<dim3(BS), blk, 0, stream>>>(xh, tmp, g1 + l * Dd, b1 + l * Dd, xh);

        // FFN in one full pass (ff1 = qh..attg region, 128 MiB)
        gemm_nt<true, false, false, true><<<dim3(128, 32, 1), blk, 0, stream>>>(
            xh, wf1T, ffbig, BS, DFFd, Dd, Dd, Dd, DFFd,
            0, 0, 0, 0, 0, 0, 1, bf1 + l * DFFd, nullptr, 0, nullptr, 0, 0, 1.0f);
        gemm_nt<true, false, false, false><<<dim3(128, 8, 1), blk, 0, stream>>>(
            ffbig, wf2T, tmp, BS, Dd, DFFd, DFFd, DFFd, Dd,
            0, 0, 0, 0, 0, 0, 1, bf2 + l * Dd, nullptr, 0, nullptr, 0, 0, 1.0f);
        add_ln<<<dim3(BS), blk, 0, stream>>>(xh, tmp, g2 + l * Dd, b2 + l * Dd, xh);
    }

    // ---- pooling + head (fp32) ----
    pool_mean<<<dim3(4, Bb), blk, 0, stream>>>(xh, mask, pooled);
    small_gemm<1><<<dim3(4, Bb), blk, 0, stream>>>(pv, Wp1, bp1, nullptr, h1v, Dd, Pp);
    small_gemm<0><<<dim3(4, Bb), blk, 0, stream>>>(h1v, Wp2, bp2, pooled, comb, Dd, Dd);
    small_gemm<2><<<dim3(4, Bb), blk, 0, stream>>>(comb, Wo1, bo1, nullptr, tvv, Dd, Dd);
    small_gemm<0><<<dim3(4, Bb), blk, 0, stream>>>(tvv, Wo2, bo2, nullptr, outp, Dd, Dd);
}